// Round 11
// baseline (1074.670 us; speedup 1.0000x reference)
//
#include <hip/hip_runtime.h>

// ---------------- problem constants ----------------
#define M_DIM 8192   // B*S = 4*2048
#define N_DIM 16384  // OUT
#define K_DIM 4096   // IN
#define QBLK  64     // bnb quant block

// GEMM geometry: 256x256 tile, BK=64, double-buffered LDS (8 regions x 16 KiB)
#define BM 256
#define BN 256
#define BK 64
#define NT (K_DIM / BK)   // 64 K-tiles

typedef short  s8v  __attribute__((ext_vector_type(8)));   // 8 bf16 (MFMA A/B frag)
typedef unsigned short u16x8 __attribute__((ext_vector_type(8)));
typedef float  f4v  __attribute__((ext_vector_type(4)));   // MFMA C/D frag

__constant__ float NF4C[16] = {
    -1.0f, -0.6961928009986877f, -0.5250730514526367f, -0.39491748809814453f,
    -0.28444138169288635f, -0.18477343022823334f, -0.09105003625154495f, 0.0f,
    0.07958029955625534f, 0.16093020141124725f, 0.24611230194568634f, 0.33791524171829224f,
    0.44070982933044434f, 0.5626170039176941f, 0.7229568362236023f, 1.0f
};

// round-to-nearest-even f32 -> bf16 bits (finite inputs only)
__device__ __forceinline__ unsigned short f2bf(float f) {
    union { float f; unsigned u; } v; v.f = f;
    unsigned r = v.u + 0x7FFFu + ((v.u >> 16) & 1u);
    return (unsigned short)(r >> 16);
}

__device__ __forceinline__ void async16(const unsigned short* g, unsigned short* l) {
    __builtin_amdgcn_global_load_lds(
        (const __attribute__((address_space(1))) void*)g,
        (__attribute__((address_space(3))) void*)l,
        16, 0, 0);
}

#define WAITVM(n)  asm volatile("s_waitcnt vmcnt(" #n ")" ::: "memory")
#define BARX()     asm volatile("s_barrier" ::: "memory")
#define PRIO1      __builtin_amdgcn_s_setprio(1)
#define PRIO0      __builtin_amdgcn_s_setprio(0)

// ---------------- prep pass 1: x fp32 -> bf16 ----------------
__global__ void convert_x_kernel(const float* __restrict__ x,
                                 unsigned short* __restrict__ o, long n) {
    long i = ((long)blockIdx.x * blockDim.x + threadIdx.x) * 8;
    long stride = (long)gridDim.x * blockDim.x * 8;
    for (; i < n; i += stride) {
        const float4* p = (const float4*)(x + i);
        float4 a = p[0], b = p[1];
        u16x8 o8;
        o8[0] = f2bf(a.x); o8[1] = f2bf(a.y); o8[2] = f2bf(a.z); o8[3] = f2bf(a.w);
        o8[4] = f2bf(b.x); o8[5] = f2bf(b.y); o8[6] = f2bf(b.z); o8[7] = f2bf(b.w);
        *(u16x8*)(o + i) = o8;
    }
}

// ---------------- prep pass 2: NF4 codes -> bf16 weights ----------------
__global__ void dequant_w_kernel(const int* __restrict__ codes,
                                 const float* __restrict__ am,
                                 unsigned short* __restrict__ o, long n) {
    __shared__ float lut[16];
    if (threadIdx.x < 16) lut[threadIdx.x] = NF4C[threadIdx.x];
    __syncthreads();
    long i = ((long)blockIdx.x * blockDim.x + threadIdx.x) * 8;
    long stride = (long)gridDim.x * blockDim.x * 8;
    for (; i < n; i += stride) {
        const int4* p = (const int4*)(codes + i);
        int4 c0 = p[0], c1 = p[1];
        float s = am[i >> 6];
        u16x8 o8;
        o8[0] = f2bf(lut[c0.x] * s); o8[1] = f2bf(lut[c0.y] * s);
        o8[2] = f2bf(lut[c0.z] * s); o8[3] = f2bf(lut[c0.w] * s);
        o8[4] = f2bf(lut[c1.x] * s); o8[5] = f2bf(lut[c1.y] * s);
        o8[6] = f2bf(lut[c1.z] * s); o8[7] = f2bf(lut[c1.w] * s);
        *(u16x8*)(o + i) = o8;
    }
}

// ---------------- 2-phase 256x256 GEMM, swizzled linear LDS ----------------
// y[m][n] = sum_k A[m][k]*B[n][k]; A [M][K], B [N][K] bf16 row-major.
// Round-10 kernel with ph0+ph1 MERGED: 2 barriers per K-tile (was 3), still
// no explicit lgkmcnt drains (compiler emits fine-grained per-MFMA waits).
// LDS: 8 regions x 16 KiB (buf0: A0=0 A1=1 B0=2 B1=3; buf1: +4). Region =
// row-major [128][64] bf16, swizzle stored_byte(row,k) = row*128 +
// ((k*2) ^ ((row&7)<<4)) -> conflict-free ds_read_b128 (round-8/10: 0).
// Staging: linear global_load_lds dest; source row = i*64 + tid/8 (coalesced
// full 128B lines), source col = ((tid&7)*8) ^ (((tid>>3)&7)<<3).
// Fragment read: qL0 = fr*128 + (kg*16 ^ ((fr&7)<<4)); qL1 = qL0 ^ 64.
// Schedule per K-tile t (stages tile t+1 into buf (t+1)&1):
//   ph0: RD A0(8),B0(4),B1(4) | STG A0' | STG B0' | MM Q00+Q01 (32) | vm4 | bar
//   ph1: RD A1(8)             | STG B1' | STG A1' | MM Q11+Q10 (32) | vm2 | bar
// Ledger (2 loads/STG, verified): vm4 @ph0-end retires A1^t (issued t-1 ph1;
// younger = t ph0's 4). vm2 @ph1-end retires B1^{t+1} (issued this phase;
// younger = A1^{t+1}'s 2) plus A0',B0' (issued ph0). WAR: every STG >=2
// barriers after its region's last read. Tail tile: vm0 then free.
__global__ __launch_bounds__(512, 2)
void gemm_2pswz_kernel(const unsigned short* __restrict__ A,
                       const unsigned short* __restrict__ B,
                       float* __restrict__ Cp) {
    __shared__ __attribute__((aligned(16))) unsigned short lds[65536]; // 128 KiB

    const int tid  = threadIdx.x;
    const int wid  = tid >> 6;
    const int lane = tid & 63;
    const int wm   = wid >> 2;   // 0..1
    const int wn   = wid & 3;    // 0..3

    // XCD-bijective swizzle (round-8/10, best measured): chunk 256 per XCD
    const int bid = blockIdx.x;
    const int wg  = (bid & 7) * 256 + (bid >> 3);
    const int bm0 = (wg >> 6) * BM;
    const int bn0 = (wg & 63) * BN;

    // staging source coords (linear dest, inverse-swizzled source column)
    const int scol = ((tid & 7) * 8) ^ (((tid >> 3) & 7) << 3);
    int Rr[2];
    Rr[0] = tid >> 3;          // rows 0..63   (instr i=0)
    Rr[1] = 64 + (tid >> 3);   // rows 64..127 (instr i=1); (row&7) unchanged

    const unsigned short* pA0[2]; const unsigned short* pA1[2];
    const unsigned short* pB0[2]; const unsigned short* pB1[2];
#pragma unroll
    for (int i = 0; i < 2; ++i) {
        pA0[i] = A + (size_t)(bm0 + Rr[i]) * K_DIM + scol;
        pA1[i] = pA0[i] + (size_t)128 * K_DIM;
        pB0[i] = B + (size_t)(bn0 + Rr[i]) * K_DIM + scol;
        pB1[i] = pB0[i] + (size_t)128 * K_DIM;
    }

    // stage one half-tile (2 global_load_lds) into region R at k-offset KO;
    // dest base is wave-uniform (HW adds lane*16)
#define STG(R, P, KO)                                                         \
    { unsigned short* d = lds + (R) * 8192 + wid * 512;                       \
      async16(P[0] + (KO), d);                                                \
      async16(P[1] + (KO), d + 4096); }

    // fragment read byte offsets (swizzled); kk=1 (k+32) flips bit 6
    const int fr = lane & 15, kg = lane >> 4;
    const int qL0 = fr * 128 + ((kg * 16) ^ ((fr & 7) << 4));
    const int qL1 = qL0 ^ 64;
    const char* ldsc = (const char*)lds;

    f4v acc[8][4];
#pragma unroll
    for (int i = 0; i < 8; ++i)
#pragma unroll
        for (int j = 0; j < 4; ++j) acc[i][j] = f4v{0.f, 0.f, 0.f, 0.f};

    s8v aset[4][2], b0set[2][2], b1set[2][2];

    // A quadrant in region R: wave wm rows wm*64 + fm*16 + fr, k = kk*32+kg*8
#define RD_A(R)                                                               \
    { const char* ba = ldsc + (R) * 16384 + wm * 8192;                        \
      _Pragma("unroll") for (int fm = 0; fm < 4; ++fm) {                      \
          aset[fm][0] = *(const s8v*)(ba + fm * 2048 + qL0);                  \
          aset[fm][1] = *(const s8v*)(ba + fm * 2048 + qL1); } }

    // B quadrant in region R: wave wn rows wn*32 + fn*16 + fr
#define RD_B(R, BS)                                                           \
    { const char* bb = ldsc + (R) * 16384 + wn * 4096;                        \
      _Pragma("unroll") for (int fn = 0; fn < 2; ++fn) {                      \
          BS[fn][0] = *(const s8v*)(bb + fn * 2048 + qL0);                    \
          BS[fn][1] = *(const s8v*)(bb + fn * 2048 + qL1); } }

#define MM(qm, qn, BS)                                                        \
    _Pragma("unroll") for (int kk = 0; kk < 2; ++kk)                          \
      _Pragma("unroll") for (int fm = 0; fm < 4; ++fm)                        \
        _Pragma("unroll") for (int fn = 0; fn < 2; ++fn)                      \
          acc[(qm)*4+fm][(qn)*2+fn] = __builtin_amdgcn_mfma_f32_16x16x32_bf16(\
            aset[fm][kk], BS[fn][kk], acc[(qm)*4+fm][(qn)*2+fn], 0, 0, 0);

    // ---- prologue: stage tile 0 into buf0; drain; barrier ----
    STG(0, pA0, 0); STG(2, pB0, 0); STG(3, pB1, 0); STG(1, pA1, 0);
    WAITVM(0);
    BARX();

    for (int t = 0; t < NT - 1; ++t) {
        const int b4 = (t & 1) * 4;
        const int o4 = 4 - b4;
        const int kn = (t + 1) * BK;

        // ---- ph0: Q00 + Q01 ----
        RD_A(b4 + 0); RD_B(b4 + 2, b0set); RD_B(b4 + 3, b1set);
        STG(o4 + 0, pA0, kn);            // A0^{t+1}
        STG(o4 + 2, pB0, kn);            // B0^{t+1}
        PRIO1; MM(0, 0, b0set); MM(0, 1, b1set); PRIO0;
        WAITVM(4); BARX();

        // ---- ph1: Q11 + Q10 ----
        RD_A(b4 + 1);
        STG(o4 + 3, pB1, kn);            // B1^{t+1}
        STG(o4 + 1, pA1, kn);            // A1^{t+1}
        PRIO1; MM(1, 1, b1set); MM(1, 0, b0set); PRIO0;
        WAITVM(2); BARX();
    }

    // ---- tail tile NT-1 (no staging; shrinking waits) ----
    {
        const int b4 = ((NT - 1) & 1) * 4;
        RD_A(b4 + 0); RD_B(b4 + 2, b0set); RD_B(b4 + 3, b1set);
        PRIO1; MM(0, 0, b0set); MM(0, 1, b1set); PRIO0;
        WAITVM(0); BARX();
        RD_A(b4 + 1);
        PRIO1; MM(1, 1, b1set); MM(1, 0, b0set); PRIO0;
    }

    // ---- epilogue: D col = lane&15, row = (lane>>4)*4 + r ----
#pragma unroll
    for (int m8 = 0; m8 < 8; ++m8) {
        const int grow = bm0 + (m8 >> 2) * 128 + wm * 64 + (m8 & 3) * 16 + (lane >> 4) * 4;
#pragma unroll
        for (int n4 = 0; n4 < 4; ++n4) {
            const int gcol = bn0 + (n4 >> 1) * 128 + wn * 32 + (n4 & 1) * 16 + (lane & 15);
            float* yp = Cp + (size_t)grow * N_DIM + gcol;
#pragma unroll
            for (int r = 0; r < 4; ++r) yp[(size_t)r * N_DIM] = acc[m8][n4][r];
        }
    }
#undef STG
#undef RD_A
#undef RD_B
#undef MM
}

// ---------------- fallback: fused dequant GEMM (no workspace needed) ----------------
__global__ void gemm_fused_kernel(const float* __restrict__ X,
                                  const int* __restrict__ W,
                                  const float* __restrict__ am,
                                  float* __restrict__ C) {
    __shared__ __attribute__((aligned(16))) unsigned short ldsA[128 * 32];
    __shared__ __attribute__((aligned(16))) unsigned short ldsB[128 * 32];
    __shared__ float lut[16];

    const int tid = threadIdx.x;
    if (tid < 16) lut[tid] = NF4C[tid];
    __syncthreads();

    const int wave = tid >> 6, lane = tid & 63;
    const int wr = wave >> 1, wc = wave & 1;
    const int bid = blockIdx.x;
    const int wg  = (bid & 7) * 1024 + (bid >> 3);
    const int bm0 = (wg >> 7) * 128;
    const int bn0 = (wg & 127) * 128;

    const int row = tid >> 2, col8 = (tid & 3) * 8;
    const float* gX0 = X + (size_t)(bm0 + row) * K_DIM + col8;
    const float* gX1 = gX0 + (size_t)64 * K_DIM;
    const int*   gW0 = W + (size_t)(bn0 + row) * K_DIM + col8;
    const int*   gW1 = gW0 + (size_t)64 * K_DIM;
    const int amRow0 = (bn0 + row) * (K_DIM / QBLK);
    const int amRow1 = (bn0 + row + 64) * (K_DIM / QBLK);

    unsigned short* sA0 = ldsA + tid * 8;
    unsigned short* sA1 = ldsA + (tid + 256) * 8;
    unsigned short* sB0 = ldsB + tid * 8;
    unsigned short* sB1 = ldsB + (tid + 256) * 8;

    f4v acc[4][4];
#pragma unroll
    for (int i = 0; i < 4; ++i)
#pragma unroll
        for (int j = 0; j < 4; ++j) acc[i][j] = f4v{0.f, 0.f, 0.f, 0.f};

    const int fr = lane & 15, kg = lane >> 4;
    const unsigned short* pa = ldsA + (wr * 64 + fr) * 32 + kg * 8;
    const unsigned short* pb = ldsB + (wc * 64 + fr) * 32 + kg * 8;

    for (int k0 = 0; k0 < K_DIM; k0 += 32) {
        float4 x0a = *(const float4*)(gX0 + k0);
        float4 x0b = *(const float4*)(gX0 + k0 + 4);
        float4 x1a = *(const float4*)(gX1 + k0);
        float4 x1b = *(const float4*)(gX1 + k0 + 4);
        int4 w0a = *(const int4*)(gW0 + k0);
        int4 w0b = *(const int4*)(gW0 + k0 + 4);
        int4 w1a = *(const int4*)(gW1 + k0);
        int4 w1b = *(const int4*)(gW1 + k0 + 4);
        float s0 = am[amRow0 + ((k0 + col8) >> 6)];
        float s1 = am[amRow1 + ((k0 + col8) >> 6)];

        u16x8 A0, A1, B0, B1;
        A0[0] = f2bf(x0a.x); A0[1] = f2bf(x0a.y); A0[2] = f2bf(x0a.z); A0[3] = f2bf(x0a.w);
        A0[4] = f2bf(x0b.x); A0[5] = f2bf(x0b.y); A0[6] = f2bf(x0b.z); A0[7] = f2bf(x0b.w);
        A1[0] = f2bf(x1a.x); A1[1] = f2bf(x1a.y); A1[2] = f2bf(x1a.z); A1[3] = f2bf(x1a.w);
        A1[4] = f2bf(x1b.x); A1[5] = f2bf(x1b.y); A1[6] = f2bf(x1b.z); A1[7] = f2bf(x1b.w);
        B0[0] = f2bf(lut[w0a.x] * s0); B0[1] = f2bf(lut[w0a.y] * s0);
        B0[2] = f2bf(lut[w0a.z] * s0); B0[3] = f2bf(lut[w0a.w] * s0);
        B0[4] = f2bf(lut[w0b.x] * s0); B0[5] = f2bf(lut[w0b.y] * s0);
        B0[6] = f2bf(lut[w0b.z] * s0); B0[7] = f2bf(lut[w0b.w] * s0);
        B1[0] = f2bf(lut[w1a.x] * s1); B1[1] = f2bf(lut[w1a.y] * s1);
        B1[2] = f2bf(lut[w1a.z] * s1); B1[3] = f2bf(lut[w1a.w] * s1);
        B1[4] = f2bf(lut[w1b.x] * s1); B1[5] = f2bf(lut[w1b.y] * s1);
        B1[6] = f2bf(lut[w1b.z] * s1); B1[7] = f2bf(lut[w1b.w] * s1);

        __syncthreads();
        *(u16x8*)sA0 = A0; *(u16x8*)sA1 = A1;
        *(u16x8*)sB0 = B0; *(u16x8*)sB1 = B1;
        __syncthreads();

        s8v a[4], b[4];
#pragma unroll
        for (int i = 0; i < 4; ++i) a[i] = *(const s8v*)(pa + i * 16 * 32);
#pragma unroll
        for (int i = 0; i < 4; ++i) b[i] = *(const s8v*)(pb + i * 16 * 32);
#pragma unroll
        for (int i = 0; i < 4; ++i)
#pragma unroll
            for (int j = 0; j < 4; ++j)
                acc[i][j] = __builtin_amdgcn_mfma_f32_16x16x32_bf16(a[i], b[j], acc[i][j], 0, 0, 0);
    }

    const int row0 = bm0 + wr * 64 + (lane >> 4) * 4;
    const int col0 = bn0 + wc * 64 + (lane & 15);
#pragma unroll
    for (int i = 0; i < 4; ++i)
#pragma unroll
        for (int j = 0; j < 4; ++j) {
            float* yp = C + (size_t)(row0 + i * 16) * N_DIM + col0 + j * 16;
#pragma unroll
            for (int r = 0; r < 4; ++r) yp[(size_t)r * N_DIM] = acc[i][j][r];
        }
}

extern "C" void kernel_launch(void* const* d_in, const int* in_sizes, int n_in,
                              void* d_out, int out_size, void* d_ws, size_t ws_size,
                              hipStream_t stream) {
    const float* x     = (const float*)d_in[0];
    const int*   codes = (const int*)d_in[1];
    const float* am    = (const float*)d_in[2];
    float* y = (float*)d_out;

    const long MK = (long)M_DIM * K_DIM;
    const long NK = (long)N_DIM * K_DIM;
    const size_t need = (size_t)(MK + NK) * sizeof(unsigned short);  // 192 MiB

    if (ws_size >= need) {
        unsigned short* xb = (unsigned short*)d_ws;
        unsigned short* wb = xb + MK;
        convert_x_kernel<<<2048, 256, 0, stream>>>(x, xb, MK);
        dequant_w_kernel<<<2048, 256, 0, stream>>>(codes, am, wb, NK);
        const int ngrid = (M_DIM / BM) * (N_DIM / BN);  // 2048
        gemm_2pswz_kernel<<<ngrid, 512, 0, stream>>>(xb, wb, y);
    } else {
        const int ngrid = (M_DIM / 128) * (N_DIM / 128); // 8192
        gemm_fused_kernel<<<ngrid, 256, 0, stream>>>(x, codes, am, y);
    }
}

// Round 13
// 610.071 us; speedup vs baseline: 1.7615x; 1.7615x over previous
//
#include <hip/hip_runtime.h>

// ---------------- problem constants ----------------
#define M_DIM 8192   // B*S = 4*2048
#define N_DIM 16384  // OUT
#define K_DIM 4096   // IN
#define QBLK  64     // bnb quant block

// i8 GEMM geometry: 256x256 tile, BK=128 i8 (region = [128 rows][128 B], the
// same byte geometry as round-10's bf16 BK=64), double-buffered (8 x 16 KiB)
#define BM 256
#define BN 256
#define IBK 128
#define INT_TILES (K_DIM / IBK)   // 32 K-tiles

typedef short  s8v  __attribute__((ext_vector_type(8)));   // 8 bf16 (fallback)
typedef unsigned short u16x8 __attribute__((ext_vector_type(8)));
typedef float  f4v  __attribute__((ext_vector_type(4)));   // f32 MFMA C/D frag
typedef int    i4v  __attribute__((ext_vector_type(4)));   // i8 MFMA A/B (16B) and i32 C/D

__constant__ float NF4C[16] = {
    -1.0f, -0.6961928009986877f, -0.5250730514526367f, -0.39491748809814453f,
    -0.28444138169288635f, -0.18477343022823334f, -0.09105003625154495f, 0.0f,
    0.07958029955625534f, 0.16093020141124725f, 0.24611230194568634f, 0.33791524171829224f,
    0.44070982933044434f, 0.5626170039176941f, 0.7229568362236023f, 1.0f
};

// round-to-nearest-even f32 -> bf16 bits (finite inputs only; fallback path)
__device__ __forceinline__ unsigned short f2bf(float f) {
    union { float f; unsigned u; } v; v.f = f;
    unsigned r = v.u + 0x7FFFu + ((v.u >> 16) & 1u);
    return (unsigned short)(r >> 16);
}

__device__ __forceinline__ void async16(const void* g, void* l) {
    __builtin_amdgcn_global_load_lds(
        (const __attribute__((address_space(1))) void*)g,
        (__attribute__((address_space(3))) void*)l,
        16, 0, 0);
}

#define WAITVM(n)  asm volatile("s_waitcnt vmcnt(" #n ")" ::: "memory")
#define BARX()     asm volatile("s_barrier" ::: "memory")
#define PRIO1      __builtin_amdgcn_s_setprio(1)
#define PRIO0      __builtin_amdgcn_s_setprio(0)

// ---------------- prep pass 1: quantize x rows to i8 (per-row scale) --------
// one block per row m; 256 threads x 16 elems. sx[m] = absmax/127.
__global__ void quant_x_kernel(const float* __restrict__ x,
                               signed char* __restrict__ xq,
                               float* __restrict__ sx) {
    const int m = blockIdx.x, t = threadIdx.x;
    const int lane = t & 63, wv = t >> 6;
    const float4* px = (const float4*)(x + (size_t)m * K_DIM + t * 16);
    float4 v0 = px[0], v1 = px[1], v2 = px[2], v3 = px[3];
    float amax = 0.f;
#define AB4(v) amax = fmaxf(amax, fmaxf(fmaxf(fabsf(v.x), fabsf(v.y)), fmaxf(fabsf(v.z), fabsf(v.w))));
    AB4(v0) AB4(v1) AB4(v2) AB4(v3)
#undef AB4
    for (int off = 32; off; off >>= 1) amax = fmaxf(amax, __shfl_xor(amax, off));
    __shared__ float red[4];
    if (lane == 0) red[wv] = amax;
    __syncthreads();
    amax = fmaxf(fmaxf(red[0], red[1]), fmaxf(red[2], red[3]));
    const float inv = (amax > 0.f) ? 127.0f / amax : 0.f;
    if (t == 0) sx[m] = amax * (1.0f / 127.0f);
    int4 o;
#define PK(a,b,c,d) ((__float2int_rn((a)*inv)&255)|((__float2int_rn((b)*inv)&255)<<8)|\
                     ((__float2int_rn((c)*inv)&255)<<16)|((__float2int_rn((d)*inv)&255)<<24))
    o.x = PK(v0.x, v0.y, v0.z, v0.w);
    o.y = PK(v1.x, v1.y, v1.z, v1.w);
    o.z = PK(v2.x, v2.y, v2.z, v2.w);
    o.w = PK(v3.x, v3.y, v3.z, v3.w);
#undef PK
    *(int4*)(xq + (size_t)m * K_DIM + t * 16) = o;
}

// ---------------- prep pass 2: NF4 codes -> i8 weights (per-row scale) ------
// one block per row o; 256 threads x 16 codes (each thread within one 64-blk).
// w = lut[code]*am[o][kb]; row scale = max_kb(am)/127 (|w| <= max am exactly).
__global__ void quant_w_kernel(const int* __restrict__ codes,
                               const float* __restrict__ am,
                               signed char* __restrict__ wq,
                               float* __restrict__ sw) {
    __shared__ float lut[16];
    __shared__ float red[4];
    const int o = blockIdx.x, t = threadIdx.x;
    const int lane = t & 63, wv = t >> 6;
    if (t < 16) lut[t] = NF4C[t];
    const float ab = am[o * (K_DIM / QBLK) + (t >> 2)];
    float amax = ab;
    for (int off = 32; off; off >>= 1) amax = fmaxf(amax, __shfl_xor(amax, off));
    if (lane == 0) red[wv] = amax;
    __syncthreads();   // also covers lut writes
    amax = fmaxf(fmaxf(red[0], red[1]), fmaxf(red[2], red[3]));
    const float inv = (amax > 0.f) ? 127.0f / amax : 0.f;
    if (t == 0) sw[o] = amax * (1.0f / 127.0f);
    const int4* pc = (const int4*)(codes + (size_t)o * K_DIM + t * 16);
    int4 c0 = pc[0], c1 = pc[1], c2 = pc[2], c3 = pc[3];
    const float s = ab * inv;
    int4 oo;
#define PKW(q) (__float2int_rn(lut[q] * s) & 255)
    oo.x = PKW(c0.x) | (PKW(c0.y) << 8) | (PKW(c0.z) << 16) | (PKW(c0.w) << 24);
    oo.y = PKW(c1.x) | (PKW(c1.y) << 8) | (PKW(c1.z) << 16) | (PKW(c1.w) << 24);
    oo.z = PKW(c2.x) | (PKW(c2.y) << 8) | (PKW(c2.z) << 16) | (PKW(c2.w) << 24);
    oo.w = PKW(c3.x) | (PKW(c3.y) << 8) | (PKW(c3.z) << 16) | (PKW(c3.w) << 24);
#undef PKW
    *(int4*)(wq + (size_t)o * K_DIM + t * 16) = oo;
}

// ---------------- 3-phase 256x256 i8 GEMM (round-10 structure, NT=32) -------
// y[m][n] = sx[m]*sw[n] * sum_k Aq[m][k]*Bq[n][k] (i8 x i8 -> i32, exact).
// BYTE-IDENTICAL geometry to round-10 bf16 kernel: region = 16 KiB =
// [128 rows][128 B] (128 i8 instead of 64 bf16), 8 regions, same 3-bit XOR
// swizzle stored_byte(row,kB) = row*128 + (kB ^ ((row&7)<<4)), same linear
// staging with inverse-swizzled coalesced source, same fragment offsets
// qL0/qL1 (qL1 = qL0^64 exact: bit-6 flip commutes with bits-4..6 mask),
// same 3-phase schedule + vmcnt ledger (verified round 10), NT = 32.
// ROUND-12 BUG FIXED: fragment-read region stride was 32768 (read past the
// 128 KiB LDS allocation for regions 4-7) -> now 16384, matching STG.
// MFMA: mfma_i32_16x16x64_i8 (A/B = 16 i8/lane, k = (lane>>4)*16+e).
__global__ __launch_bounds__(512, 2)
void gemm_i8_kernel(const signed char* __restrict__ A,
                    const signed char* __restrict__ B,
                    const float* __restrict__ sx,
                    const float* __restrict__ sw,
                    float* __restrict__ Cp) {
    __shared__ __attribute__((aligned(16))) unsigned char lds[131072]; // 128 KiB

    const int tid  = threadIdx.x;
    const int wid  = tid >> 6;
    const int lane = tid & 63;
    const int wm   = wid >> 2;   // 0..1
    const int wn   = wid & 3;    // 0..3

    // XCD-bijective swizzle (round-8/10 best): chunk 256 per XCD
    const int bid = blockIdx.x;
    const int wg  = (bid & 7) * 256 + (bid >> 3);
    const int bm0 = (wg >> 6) * BM;
    const int bn0 = (wg & 63) * BN;

    // staging source coords (linear dest, inverse-swizzled source chunk)
    const int scol = (((tid & 7) ^ ((tid >> 3) & 7)) << 4);  // bytes within row
    int Rr[2];
    Rr[0] = tid >> 3;          // rows 0..63   (instr i=0)
    Rr[1] = 64 + (tid >> 3);   // rows 64..127 (instr i=1); (row&7) unchanged

    const signed char* pA0[2]; const signed char* pA1[2];
    const signed char* pB0[2]; const signed char* pB1[2];
#pragma unroll
    for (int i = 0; i < 2; ++i) {
        pA0[i] = A + (size_t)(bm0 + Rr[i]) * K_DIM + scol;
        pA1[i] = pA0[i] + (size_t)128 * K_DIM;
        pB0[i] = B + (size_t)(bn0 + Rr[i]) * K_DIM + scol;
        pB1[i] = pB0[i] + (size_t)128 * K_DIM;
    }

    // stage one half-tile (2 global_load_lds) into region R at k-offset KO
#define STG(R, P, KO)                                                         \
    { unsigned char* d = lds + (R) * 16384 + wid * 1024;                      \
      async16(P[0] + (KO), d);                                                \
      async16(P[1] + (KO), d + 8192); }

    // fragment read byte offsets (swizzled); kk=1 (k-bytes +64) flips bit 6
    const int fr = lane & 15, kg = lane >> 4;
    const int qL0 = fr * 128 + ((kg * 16) ^ ((fr & 7) << 4));
    const int qL1 = qL0 ^ 64;
    const char* ldsc = (const char*)lds;

    i4v acc[8][4];
#pragma unroll
    for (int i = 0; i < 8; ++i)
#pragma unroll
        for (int j = 0; j < 4; ++j) acc[i][j] = i4v{0, 0, 0, 0};

    i4v aset[4][2], b0set[2][2], b1set[2][2];

    // A quadrant in region R: wave wm rows wm*64 + fm*16 + fr, k = kk*64+kg*16
#define RD_A(R)                                                               \
    { const char* ba = ldsc + (R) * 16384 + wm * 8192;                        \
      _Pragma("unroll") for (int fm = 0; fm < 4; ++fm) {                      \
          aset[fm][0] = *(const i4v*)(ba + fm * 2048 + qL0);                  \
          aset[fm][1] = *(const i4v*)(ba + fm * 2048 + qL1); } }

    // B quadrant in region R: wave wn rows wn*32 + fn*16 + fr
#define RD_B(R, BS)                                                           \
    { const char* bb = ldsc + (R) * 16384 + wn * 4096;                        \
      _Pragma("unroll") for (int fn = 0; fn < 2; ++fn) {                      \
          BS[fn][0] = *(const i4v*)(bb + fn * 2048 + qL0);                    \
          BS[fn][1] = *(const i4v*)(bb + fn * 2048 + qL1); } }

#define MM(qm, qn, BS)                                                        \
    _Pragma("unroll") for (int kk = 0; kk < 2; ++kk)                          \
      _Pragma("unroll") for (int fm = 0; fm < 4; ++fm)                        \
        _Pragma("unroll") for (int fn = 0; fn < 2; ++fn)                      \
          acc[(qm)*4+fm][(qn)*2+fn] = __builtin_amdgcn_mfma_i32_16x16x64_i8(  \
            aset[fm][kk], BS[fn][kk], acc[(qm)*4+fm][(qn)*2+fn], 0, 0, 0);

    // regions: buf0 A0=0 A1=1 B0=2 B1=3 ; buf1 = +4
    // ---- prologue: stage tile 0 into buf0; drain; barrier ----
    STG(0, pA0, 0); STG(2, pB0, 0); STG(3, pB1, 0); STG(1, pA1, 0);
    WAITVM(0);
    BARX();

    for (int t = 0; t < INT_TILES - 1; ++t) {
        const int b4 = (t & 1) * 4;
        const int o4 = 4 - b4;
        const int kn = (t + 1) * IBK;

        // ---- ph0: Q00 ----
        RD_A(b4 + 0); RD_B(b4 + 2, b0set);
        STG(o4 + 0, pA0, kn);            // A0^{t+1}
        PRIO1; MM(0, 0, b0set); PRIO0;
        WAITVM(4); BARX();

        // ---- ph1: Q01 ----
        RD_B(b4 + 3, b1set);
        STG(o4 + 2, pB0, kn);            // B0^{t+1}
        PRIO1; MM(0, 1, b1set); PRIO0;
        WAITVM(4); BARX();

        // ---- ph23: Q11 then Q10 ----
        RD_A(b4 + 1);
        STG(o4 + 3, pB1, kn);            // B1^{t+1}
        PRIO1; MM(1, 1, b1set); PRIO0;
        STG(o4 + 1, pA1, kn);            // A1^{t+1}
        PRIO1; MM(1, 0, b0set); PRIO0;
        WAITVM(4); BARX();
    }

    // ---- tail tile (no staging; shrinking waits) ----
    {
        const int b4 = ((INT_TILES - 1) & 1) * 4;
        RD_A(b4 + 0); RD_B(b4 + 2, b0set);
        PRIO1; MM(0, 0, b0set); PRIO0;
        WAITVM(2); BARX();
        RD_B(b4 + 3, b1set);
        PRIO1; MM(0, 1, b1set); PRIO0;
        WAITVM(0); BARX();
        RD_A(b4 + 1);
        PRIO1; MM(1, 1, b1set); MM(1, 0, b0set); PRIO0;
    }

    // ---- epilogue: y = sx[row]*sw[col]*acc; D col = lane&15, row = (lane>>4)*4+r
#pragma unroll
    for (int m8 = 0; m8 < 8; ++m8) {
        const int grow = bm0 + (m8 >> 2) * 128 + wm * 64 + (m8 & 3) * 16 + (lane >> 4) * 4;
        float sxr[4];
#pragma unroll
        for (int r = 0; r < 4; ++r) sxr[r] = sx[grow + r];
#pragma unroll
        for (int n4 = 0; n4 < 4; ++n4) {
            const int gcol = bn0 + (n4 >> 1) * 128 + wn * 32 + (n4 & 1) * 16 + (lane & 15);
            const float swc = sw[gcol];
            float* yp = Cp + (size_t)grow * N_DIM + gcol;
#pragma unroll
            for (int r = 0; r < 4; ++r)
                yp[(size_t)r * N_DIM] = sxr[r] * swc * (float)acc[m8][n4][r];
        }
    }
#undef STG
#undef RD_A
#undef RD_B
#undef MM
}

// ---------------- fallback: fused dequant bf16 GEMM (no workspace needed) ----
__global__ void gemm_fused_kernel(const float* __restrict__ X,
                                  const int* __restrict__ W,
                                  const float* __restrict__ am,
                                  float* __restrict__ C) {
    __shared__ __attribute__((aligned(16))) unsigned short ldsA[128 * 32];
    __shared__ __attribute__((aligned(16))) unsigned short ldsB[128 * 32];
    __shared__ float lut[16];

    const int tid = threadIdx.x;
    if (tid < 16) lut[tid] = NF4C[tid];
    __syncthreads();

    const int wave = tid >> 6, lane = tid & 63;
    const int wr = wave >> 1, wc = wave & 1;
    const int bid = blockIdx.x;
    const int wg  = (bid & 7) * 1024 + (bid >> 3);
    const int bm0 = (wg >> 7) * 128;
    const int bn0 = (wg & 127) * 128;

    const int row = tid >> 2, col8 = (tid & 3) * 8;
    const float* gX0 = X + (size_t)(bm0 + row) * K_DIM + col8;
    const float* gX1 = gX0 + (size_t)64 * K_DIM;
    const int*   gW0 = W + (size_t)(bn0 + row) * K_DIM + col8;
    const int*   gW1 = gW0 + (size_t)64 * K_DIM;
    const int amRow0 = (bn0 + row) * (K_DIM / QBLK);
    const int amRow1 = (bn0 + row + 64) * (K_DIM / QBLK);

    unsigned short* sA0 = ldsA + tid * 8;
    unsigned short* sA1 = ldsA + (tid + 256) * 8;
    unsigned short* sB0 = ldsB + tid * 8;
    unsigned short* sB1 = ldsB + (tid + 256) * 8;

    f4v acc[4][4];
#pragma unroll
    for (int i = 0; i < 4; ++i)
#pragma unroll
        for (int j = 0; j < 4; ++j) acc[i][j] = f4v{0.f, 0.f, 0.f, 0.f};

    const int fr = lane & 15, kg = lane >> 4;
    const unsigned short* pa = ldsA + (wr * 64 + fr) * 32 + kg * 8;
    const unsigned short* pb = ldsB + (wc * 64 + fr) * 32 + kg * 8;

    for (int k0 = 0; k0 < K_DIM; k0 += 32) {
        float4 x0a = *(const float4*)(gX0 + k0);
        float4 x0b = *(const float4*)(gX0 + k0 + 4);
        float4 x1a = *(const float4*)(gX1 + k0);
        float4 x1b = *(const float4*)(gX1 + k0 + 4);
        int4 w0a = *(const int4*)(gW0 + k0);
        int4 w0b = *(const int4*)(gW0 + k0 + 4);
        int4 w1a = *(const int4*)(gW1 + k0);
        int4 w1b = *(const int4*)(gW1 + k0 + 4);
        float s0 = am[amRow0 + ((k0 + col8) >> 6)];
        float s1 = am[amRow1 + ((k0 + col8) >> 6)];

        u16x8 A0, A1, B0, B1;
        A0[0] = f2bf(x0a.x); A0[1] = f2bf(x0a.y); A0[2] = f2bf(x0a.z); A0[3] = f2bf(x0a.w);
        A0[4] = f2bf(x0b.x); A0[5] = f2bf(x0b.y); A0[6] = f2bf(x0b.z); A0[7] = f2bf(x0b.w);
        A1[0] = f2bf(x1a.x); A1[1] = f2bf(x1a.y); A1[2] = f2bf(x1a.z); A1[3] = f2bf(x1a.w);
        A1[4] = f2bf(x1b.x); A1[5] = f2bf(x1b.y); A1[6] = f2bf(x1b.z); A1[7] = f2bf(x1b.w);
        B0[0] = f2bf(lut[w0a.x] * s0); B0[1] = f2bf(lut[w0a.y] * s0);
        B0[2] = f2bf(lut[w0a.z] * s0); B0[3] = f2bf(lut[w0a.w] * s0);
        B0[4] = f2bf(lut[w0b.x] * s0); B0[5] = f2bf(lut[w0b.y] * s0);
        B0[6] = f2bf(lut[w0b.z] * s0); B0[7] = f2bf(lut[w0b.w] * s0);
        B1[0] = f2bf(lut[w1a.x] * s1); B1[1] = f2bf(lut[w1a.y] * s1);
        B1[2] = f2bf(lut[w1a.z] * s1); B1[3] = f2bf(lut[w1a.w] * s1);
        B1[4] = f2bf(lut[w1b.x] * s1); B1[5] = f2bf(lut[w1b.y] * s1);
        B1[6] = f2bf(lut[w1b.z] * s1); B1[7] = f2bf(lut[w1b.w] * s1);

        __syncthreads();
        *(u16x8*)sA0 = A0; *(u16x8*)sA1 = A1;
        *(u16x8*)sB0 = B0; *(u16x8*)sB1 = B1;
        __syncthreads();

        s8v a[4], b[4];
#pragma unroll
        for (int i = 0; i < 4; ++i) a[i] = *(const s8v*)(pa + i * 16 * 32);
#pragma unroll
        for (int i = 0; i < 4; ++i) b[i] = *(const s8v*)(pb + i * 16 * 32);
#pragma unroll
        for (int i = 0; i < 4; ++i)
#pragma unroll
            for (int j = 0; j < 4; ++j)
                acc[i][j] = __builtin_amdgcn_mfma_f32_16x16x32_bf16(a[i], b[j], acc[i][j], 0, 0, 0);
    }

    const int row0 = bm0 + wr * 64 + (lane >> 4) * 4;
    const int col0 = bn0 + wc * 64 + (lane & 15);
#pragma unroll
    for (int i = 0; i < 4; ++i)
#pragma unroll
        for (int j = 0; j < 4; ++j) {
            float* yp = C + (size_t)(row0 + i * 16) * N_DIM + col0 + j * 16;
#pragma unroll
            for (int r = 0; r < 4; ++r) yp[(size_t)r * N_DIM] = acc[i][j][r];
        }
}

extern "C" void kernel_launch(void* const* d_in, const int* in_sizes, int n_in,
                              void* d_out, int out_size, void* d_ws, size_t ws_size,
                              hipStream_t stream) {
    const float* x     = (const float*)d_in[0];
    const int*   codes = (const int*)d_in[1];
    const float* am    = (const float*)d_in[2];
    float* y = (float*)d_out;

    const size_t MK = (size_t)M_DIM * K_DIM;   // 33,554,432
    const size_t NK = (size_t)N_DIM * K_DIM;   // 67,108,864
    const size_t need = MK + NK + (M_DIM + N_DIM) * sizeof(float);

    if (ws_size >= need) {
        signed char* xq = (signed char*)d_ws;
        signed char* wq = xq + MK;
        float* sx = (float*)(wq + NK);
        float* sw = sx + M_DIM;
        quant_x_kernel<<<M_DIM, 256, 0, stream>>>(x, xq, sx);
        quant_w_kernel<<<N_DIM, 256, 0, stream>>>(codes, am, wq, sw);
        const int ngrid = (M_DIM / BM) * (N_DIM / BN);  // 2048
        gemm_i8_kernel<<<ngrid, 512, 0, stream>>>(xq, wq, sx, sw, y);
    } else {
        const int ngrid = (M_DIM / 128) * (N_DIM / 128); // 8192
        gemm_fused_kernel<<<ngrid, 256, 0, stream>>>(x, codes, am, y);
    }
}